// Round 11
// baseline (550.956 us; speedup 1.0000x reference)
//
#include <hip/hip_runtime.h>

#define B_    256
#define T_    2048
#define F_    37
#define TF    111   // 3F
#define U_    32
#define TU    96    // 3U
#define D_    16

#define KP    128   // padded K for MFMA
#define XSTR  136   // LDS row stride in bf16 (272 B)
#define MTILE 128   // timesteps per tile

#define L2E 1.4426950408889634f

typedef __attribute__((ext_vector_type(8))) short short8;
typedef __attribute__((ext_vector_type(4))) float f32x4;
typedef __attribute__((ext_vector_type(2))) float f32x2;

__device__ __forceinline__ float fast_exp2(float x) {
    float r; asm("v_exp_f32 %0, %1" : "=v"(r) : "v"(x)); return r;
}
__device__ __forceinline__ float fast_rcp(float x) {
    float r; asm("v_rcp_f32 %0, %1" : "=v"(r) : "v"(x)); return r;
}
__device__ __forceinline__ float sigmoid_fast(float x) {
    return fast_rcp(1.f + fast_exp2(-L2E * x));
}
__device__ __forceinline__ float rdlane(float v, int k) {
    return __uint_as_float(__builtin_amdgcn_readlane(__float_as_uint(v), k));
}
// every lane gets its cross-32 partner's value (hedge: partner = p0+p1-own)
__device__ __forceinline__ float swap_half(float x) {
    unsigned xi = __float_as_uint(x);
    auto p = __builtin_amdgcn_permlane32_swap(xi, xi, false, false);
    float f0 = __uint_as_float(p[0]);
    float f1 = __uint_as_float(p[1]);
    return (f0 + f1) - x;
}
__device__ __forceinline__ float bf2f(unsigned short u) {
    return __uint_as_float(((unsigned)u) << 16);
}
__device__ __forceinline__ unsigned short f2bf_rne(float x) {
    unsigned u = __float_as_uint(x);
    return (unsigned short)((u + 0x7FFFu + ((u >> 16) & 1u)) >> 16);
}

// packed f32 math, all-VGPR operands: d = (s0.lo*s1.lo[+d.lo], s0.hi*s1.hi[+d.hi])
#define PKMULV(d, hq, w) \
    asm("v_pk_mul_f32 %0, %1, %2" : "=v"(d) : "v"(hq), "v"(w))
#define PKFMAV(d, hq, w) \
    asm("v_pk_fma_f32 %0, %1, %2, %0" : "+v"(d) : "v"(hq), "v"(w))
#define PKADD(d, a, b) \
    asm("v_pk_add_f32 %0, %1, %2" : "=v"(d) : "v"(a), "v"(b))

#define SCHED_FENCE() __builtin_amdgcn_sched_barrier(0)
#define MEM_FENCE()   asm volatile("" ::: "memory")

// ============================================================================
// FUSED kernel: 256 blocks (one per batch) x 256 threads (4 waves, 1/SIMD).
//
// Phase 1 (all 4 waves): compute xz[b][t][0:96] = x[b,t]@K + b_in for this
// block's OWN batch only (ntiles = ceil(len/128) tiles, ~8 avg). Identical
// tile math to the old xz kernel (wave w handles rows w*32..w*32+31). Cost
// ~10-15 us paid in parallel on all 256 CUs — replacing the ~95 us wall the
// separate 1024-block dispatch cost (r4/r9/r10 measured: that wall was
// neither data-proportional nor per-block prologue; fusing deletes it).
//
// Phase 2 (wave 0 only; waves 1-3 exit — no barriers after, so no hang):
// rec13 recurrence verbatim (407.9 us verified r9/r10): LDS-crossbar h
// broadcast (1 ds_write + 8 uniform ds_read_b128; readlane crossbar
// occupancy was the hidden ~300 cyc/step), R2-R5 pinned schedule.
// Block's phase-1 global writes are visible to wave 0: __syncthreads drains
// vmcnt before s_barrier + threadfence_block; same CU => same L2.
// ============================================================================
__global__ __attribute__((amdgpu_flat_work_group_size(256, 256),
                          amdgpu_waves_per_eu(1, 1)))
void gru_fused_kernel(
    const float* __restrict__ dt,
    const float* __restrict__ values,
    const int*   __restrict__ meas,
    const float* __restrict__ kern,
    const float* __restrict__ bias,
    const float* __restrict__ demo,
    const int*   __restrict__ lengths,
    const float* __restrict__ W1,
    const float* __restrict__ b1,
    const float* __restrict__ W2,
    const float* __restrict__ b2,
    const float* __restrict__ rec_kernel,
    const float* __restrict__ Wo,
    const float* __restrict__ bo,
    unsigned short* __restrict__ xz,
    float* __restrict__ out)
{
    __shared__ unsigned short sX[MTILE][XSTR];   // 34816 B
    __shared__ unsigned short sKT[TU][XSTR];     // 26112 B
    __shared__ float sH[64];

    const int b    = blockIdx.x;
    const int tid  = threadIdx.x;
    const int wave = tid >> 6;
    const int lane = tid & 63;
    const int len  = lengths[b];

    // ---------------- Phase 1: xz for this batch ----------------
    {
        const int lr = lane & 15;          // A-row / B-col / D-col
        const int lk = (lane >> 4) * 8;    // k offset within frag

        // coalesced sKT fill: sKT[j][k] = bf16(kern[k][j]), zero for k>=TF
        for (int idx = tid; idx < TU * KP; idx += 256) {
            int k = idx / TU;
            int j = idx - k * TU;
            sKT[j][k] = (k < TF) ? f2bf_rne(kern[k * TU + j]) : (unsigned short)0;
        }
        // zero sX pad region once (cols TF..KP-1 never rewritten)
        for (int i = tid; i < MTILE * (KP - TF); i += 256) {
            int t = i / (KP - TF), p = i - t * (KP - TF);
            sX[t][TF + p] = 0;
        }
        __syncthreads();

        float bi[6];
        #pragma unroll
        for (int n = 0; n < 6; ++n) bi[n] = bias[n * 16 + lr];
        short8 bfr[6][4];
        #pragma unroll
        for (int n = 0; n < 6; ++n)
            #pragma unroll
            for (int kc = 0; kc < 4; ++kc)
                bfr[n][kc] = *(const short8*)&sKT[n * 16 + lr][kc * 32 + lk];

        const int ntiles = (len + MTILE - 1) / MTILE;   // block-uniform
        for (int it = 0; it < ntiles; ++it) {
            const int t0 = it * MTILE;
            __syncthreads();    // protect sX against previous tile's readers

            // single merged staging pass: values | meas | dt share t,f math
            for (int i = tid; i < MTILE * F_; i += 256) {
                int t = i / F_, f = i - t * F_;
                size_t g = ((size_t)b * T_ + (t0 + t)) * F_ + f;
                sX[t][f]          = f2bf_rne(values[g]);
                sX[t][F_ + f]     = meas[g] ? (unsigned short)0x3F80 : (unsigned short)0;
                sX[t][2 * F_ + f] = f2bf_rne(dt[g]);
            }
            __syncthreads();

            f32x4 acc[2][6];
            #pragma unroll
            for (int m = 0; m < 2; ++m)
                #pragma unroll
                for (int n = 0; n < 6; ++n) acc[m][n] = (f32x4){0.f, 0.f, 0.f, 0.f};

            #pragma unroll
            for (int kc = 0; kc < 4; ++kc) {
                short8 a0 = *(const short8*)&sX[wave * 32 + lr][kc * 32 + lk];
                short8 a1 = *(const short8*)&sX[wave * 32 + 16 + lr][kc * 32 + lk];
                #pragma unroll
                for (int n = 0; n < 6; ++n) {
                    acc[0][n] = __builtin_amdgcn_mfma_f32_16x16x32_bf16(a0, bfr[n][kc], acc[0][n], 0, 0, 0);
                    acc[1][n] = __builtin_amdgcn_mfma_f32_16x16x32_bf16(a1, bfr[n][kc], acc[1][n], 0, 0, 0);
                }
            }

            #pragma unroll
            for (int m = 0; m < 2; ++m) {
                #pragma unroll
                for (int r = 0; r < 4; ++r) {
                    int t = t0 + wave * 32 + m * 16 + (lane >> 4) * 4 + r;
                    unsigned short* dst = &xz[((size_t)b * T_ + t) * TU + lr];
                    #pragma unroll
                    for (int n = 0; n < 6; ++n)
                        dst[n * 16] = f2bf_rne(acc[m][n][r] + bi[n]);
                }
            }
        }

        __threadfence_block();   // block-level visibility of xz writes
        __syncthreads();         // + vmcnt(0) drain before the barrier
    }

    if (wave != 0) return;       // no barriers below — safe early exit

    // ---------------- Phase 2: recurrence (rec13 verbatim) ----------------
    const int l   = lane;
    const int lc  = l & 31;
    const bool lower = (l < 32);

    // wpA[m] = -L2E * (RK[2m][l],    RK[2m+1][l])      (z col l<32 | r col)
    // wpB[m] = 2L2E * (RK[2m][64+lc],RK[2m+1][64+lc])  (h col)
    f32x2 wpA[16], wpB[16];
    #pragma unroll
    for (int m = 0; m < 16; ++m) {
        wpA[m] = (f32x2){-L2E * rec_kernel[(2 * m) * TU + l],
                         -L2E * rec_kernel[(2 * m + 1) * TU + l]};
        wpB[m] = (f32x2){2.f * L2E * rec_kernel[(2 * m) * TU + 64 + lc],
                         2.f * L2E * rec_kernel[(2 * m + 1) * TU + 64 + lc]};
    }
    float rbA = -L2E * bias[TU + l];
    float rbB = 2.f * L2E * bias[TU + 64 + lc];
    #pragma unroll
    for (int m = 0; m < 16; ++m) {
        asm volatile("" : "+v"(wpA[m]));
        asm volatile("" : "+v"(wpB[m]));
    }
    asm volatile("" : "+v"(rbA), "+v"(rbB));

    // h0 = relu(demo@W1+b1)@W2+b2
    float av = 0.f;
    if (l < U_) {
        float a = b1[l];
        #pragma unroll
        for (int d = 0; d < D_; ++d) a += demo[b * D_ + d] * W1[d * U_ + l];
        av = fmaxf(a, 0.f);
    }
    float hv = b2[lc];
    #pragma unroll
    for (int k = 0; k < U_; ++k) hv += rdlane(av, k) * W2[k * U_ + lc];

    const unsigned short* xp = xz + (size_t)b * T_ * TU;
    unsigned short rA[4], rB[4];

    auto issue4 = [&](int tg) {
        #pragma unroll
        for (int i = 0; i < 4; ++i) {
            int t = tg + i; t = (t < len) ? t : (len - 1);
            rA[i] = xp[(size_t)t * TU + l];        // x_z (l<32) | x_r (l>=32)
            rB[i] = xp[(size_t)t * TU + 64 + lc];  // x_h
        }
    };

    typedef union { f32x4 q; f32x2 d[2]; } qd_u;

    // xApre = -L2E*xA + rbA ; xBpre = 2L2E*xB   (precomputed by caller)
    auto step = [&](float xApre, float xBpre) {
        // R1: broadcast h via LDS: write own slot, read back 32 h's as 8 b128
        sH[l] = hv;
        MEM_FENCE();                      // DS pipe is in-order per wave: RAW ok
        qd_u hq[8];
        #pragma unroll
        for (int q = 0; q < 8; ++q)
            hq[q].q = *(const f32x4*)&sH[4 * q];   // uniform addr = broadcast
        MEM_FENCE();
        SCHED_FENCE();
        // R2: A-path matvec -> recA -> exp   (hd[m] = hq[m>>1].d[m&1])
        f32x2 aA0 = (f32x2){xApre, 0.f}, aA1, aA2, aA3;
        PKFMAV(aA0, hq[0].d[0], wpA[0]);
        PKMULV(aA1, hq[0].d[1], wpA[1]);
        PKMULV(aA2, hq[1].d[0], wpA[2]);
        PKMULV(aA3, hq[1].d[1], wpA[3]);
        #pragma unroll
        for (int g = 1; g < 4; ++g) {
            PKFMAV(aA0, hq[2 * g].d[0],     wpA[4 * g]);
            PKFMAV(aA1, hq[2 * g].d[1],     wpA[4 * g + 1]);
            PKFMAV(aA2, hq[2 * g + 1].d[0], wpA[4 * g + 2]);
            PKFMAV(aA3, hq[2 * g + 1].d[1], wpA[4 * g + 3]);
        }
        f32x2 tA01, tA23, tA;
        PKADD(tA01, aA0, aA1); PKADD(tA23, aA2, aA3); PKADD(tA, tA01, tA23);
        float recA = tA.x + tA.y;
        float eA = fast_exp2(recA);
        SCHED_FENCE();
        // R3: B-path first half — fills exp latency
        f32x2 aB0 = (f32x2){rbB, 0.f}, aB1, aB2, aB3;
        PKFMAV(aB0, hq[0].d[0], wpB[0]);
        PKMULV(aB1, hq[0].d[1], wpB[1]);
        PKMULV(aB2, hq[1].d[0], wpB[2]);
        PKMULV(aB3, hq[1].d[1], wpB[3]);
        PKFMAV(aB0, hq[2].d[0], wpB[4]);
        PKFMAV(aB1, hq[2].d[1], wpB[5]);
        PKFMAV(aB2, hq[3].d[0], wpB[6]);
        PKFMAV(aB3, hq[3].d[1], wpB[7]);
        SCHED_FENCE();
        float zr = fast_rcp(1.f + eA);       // z (l<32) | r (l>=32)
        SCHED_FENCE();
        // R4: B-path second half + tree — fills rcp latency
        #pragma unroll
        for (int g = 2; g < 4; ++g) {
            PKFMAV(aB0, hq[2 * g].d[0],     wpB[4 * g]);
            PKFMAV(aB1, hq[2 * g].d[1],     wpB[4 * g + 1]);
            PKFMAV(aB2, hq[2 * g + 1].d[0], wpB[4 * g + 2]);
            PKFMAV(aB3, hq[2 * g + 1].d[1], wpB[4 * g + 3]);
        }
        f32x2 tB01, tB23, tB;
        PKADD(tB01, aB0, aB1); PKADD(tB23, aB2, aB3); PKADD(tB, tB01, tB23);
        float recB = tB.x + tB.y;
        SCHED_FENCE();
        // R5: tail
        float sw = swap_half(zr);            // partner's value
        float z  = lower ? zr : sw;
        float r  = lower ? sw : zr;
        float u2 = fmaf(r, recB, xBpre);     // 2L2E*(xB + r*rec_h)
        float e2 = fast_exp2(u2);
        float hh = fmaf(-2.f, fast_rcp(e2 + 1.f), 1.f);  // tanh
        hv = fmaf(z, hv - hh, hh);
    };

    issue4(0);
    const int full = len & ~3;
    for (int tg = 0; tg < full; tg += 4) {
        float pA0 = fmaf(bf2f(rA[0]), -L2E, rbA), pB0 = bf2f(rB[0]) * (2.f * L2E);
        float pA1 = fmaf(bf2f(rA[1]), -L2E, rbA), pB1 = bf2f(rB[1]) * (2.f * L2E);
        float pA2 = fmaf(bf2f(rA[2]), -L2E, rbA), pB2 = bf2f(rB[2]) * (2.f * L2E);
        float pA3 = fmaf(bf2f(rA[3]), -L2E, rbA), pB3 = bf2f(rB[3]) * (2.f * L2E);
        issue4(tg + 4);                        // prefetch next group
        step(pA0, pB0); step(pA1, pB1); step(pA2, pB2); step(pA3, pB3);
    }
    const int rem = len - full;
    if (rem > 0) step(fmaf(bf2f(rA[0]), -L2E, rbA), bf2f(rB[0]) * (2.f * L2E));
    if (rem > 1) step(fmaf(bf2f(rA[1]), -L2E, rbA), bf2f(rB[1]) * (2.f * L2E));
    if (rem > 2) step(fmaf(bf2f(rA[2]), -L2E, rbA), bf2f(rB[2]) * (2.f * L2E));

    float v = (l < U_) ? hv * Wo[l] : 0.f;
    v += __shfl_xor(v, 16);
    v += __shfl_xor(v, 8);
    v += __shfl_xor(v, 4);
    v += __shfl_xor(v, 2);
    v += __shfl_xor(v, 1);
    if (l == 0) out[b] = sigmoid_fast(v + bo[0]);
}

extern "C" void kernel_launch(void* const* d_in, const int* in_sizes, int n_in,
                              void* d_out, int out_size, void* d_ws, size_t ws_size,
                              hipStream_t stream) {
    const float* demo       = (const float*)d_in[0];
    const float* dt         = (const float*)d_in[1];
    const float* values     = (const float*)d_in[2];
    const int*   meas       = (const int*)  d_in[3];
    const int*   lengths    = (const int*)  d_in[4];
    const float* W1         = (const float*)d_in[5];
    const float* b1         = (const float*)d_in[6];
    const float* W2         = (const float*)d_in[7];
    const float* b2         = (const float*)d_in[8];
    const float* kern       = (const float*)d_in[9];
    const float* rec_kernel = (const float*)d_in[10];
    const float* bias       = (const float*)d_in[11];
    const float* Wo         = (const float*)d_in[12];
    const float* bo         = (const float*)d_in[13];
    float* out = (float*)d_out;

    unsigned short* xz = (unsigned short*)d_ws;   // 100.7 MB, fits (validated)
    hipLaunchKernelGGL(gru_fused_kernel, dim3(B_), dim3(256), 0, stream,
                       dt, values, meas, kern, bias, demo, lengths,
                       W1, b1, W2, b2, rec_kernel, Wo, bo, xz, out);
}

// Round 12
// 428.225 us; speedup vs baseline: 1.2866x; 1.2866x over previous
//
#include <hip/hip_runtime.h>

#define B_    256
#define T_    2048
#define F_    37
#define TF    111   // 3F
#define U_    32
#define TU    96    // 3U
#define D_    16

#define KP    128   // padded K for MFMA
#define XSTR  136   // LDS row stride in bf16 (staging)
#define XZSTR 102   // LDS row stride of xz tile (204B: rows land on distinct banks)
#define MTILE 128   // timesteps per tile

#define L2E 1.4426950408889634f

typedef __attribute__((ext_vector_type(8))) short short8;
typedef __attribute__((ext_vector_type(4))) float f32x4;
typedef __attribute__((ext_vector_type(2))) float f32x2;

__device__ __forceinline__ float fast_exp2(float x) {
    float r; asm("v_exp_f32 %0, %1" : "=v"(r) : "v"(x)); return r;
}
__device__ __forceinline__ float fast_rcp(float x) {
    float r; asm("v_rcp_f32 %0, %1" : "=v"(r) : "v"(x)); return r;
}
__device__ __forceinline__ float sigmoid_fast(float x) {
    return fast_rcp(1.f + fast_exp2(-L2E * x));
}
__device__ __forceinline__ float rdlane(float v, int k) {
    return __uint_as_float(__builtin_amdgcn_readlane(__float_as_uint(v), k));
}
// every lane gets its cross-32 partner's value (hedge: partner = p0+p1-own)
__device__ __forceinline__ float swap_half(float x) {
    unsigned xi = __float_as_uint(x);
    auto p = __builtin_amdgcn_permlane32_swap(xi, xi, false, false);
    float f0 = __uint_as_float(p[0]);
    float f1 = __uint_as_float(p[1]);
    return (f0 + f1) - x;
}
__device__ __forceinline__ float bf2f(unsigned short u) {
    return __uint_as_float(((unsigned)u) << 16);
}
__device__ __forceinline__ unsigned short f2bf_rne(float x) {
    unsigned u = __float_as_uint(x);
    return (unsigned short)((u + 0x7FFFu + ((u >> 16) & 1u)) >> 16);
}

// packed f32 math, all-VGPR operands
#define PKMULV(d, hq, w) \
    asm("v_pk_mul_f32 %0, %1, %2" : "=v"(d) : "v"(hq), "v"(w))
#define PKFMAV(d, hq, w) \
    asm("v_pk_fma_f32 %0, %1, %2, %0" : "+v"(d) : "v"(hq), "v"(w))
#define PKADD(d, a, b) \
    asm("v_pk_add_f32 %0, %1, %2" : "=v"(d) : "v"(a), "v"(b))

#define SCHED_FENCE() __builtin_amdgcn_sched_barrier(0)
#define MEM_FENCE()   asm volatile("" ::: "memory")

// ============================================================================
// Pipelined fused kernel: 256 blocks (one per batch) x 256 threads (4 waves).
//
// r11 measured that putting xz computation IN FRONT of the recurrence costs
// the longest block 225 us of serial latency-bound staging. Here it runs
// BEHIND instead: per tile k, wave 0 executes 128 recurrence steps (~61K cyc)
// on LDS buffer k&1 while waves 1-3 stage+MFMA tile k+1 (~15-30K cyc) into
// buffer (k+1)&1 — one __syncthreads per tile, both wave-uniform paths
// execute the same barrier count. xz never goes to global (-52MB wr/-50MB rd).
// Each producer wave stages only the rows its own MFMA reads -> wave-internal
// DS ordering, no intra-tile cross-wave sync. Chunk map: wave1->{0,3},
// wave2->{1}, wave3->{2}. Prologue: all 4 waves build tile 0 (~12 us).
// Phase 2 math = rec13 verbatim (407.9 us verified r9/r10), reads from LDS.
// ============================================================================
__global__ __attribute__((amdgpu_flat_work_group_size(256, 256),
                          amdgpu_waves_per_eu(1, 1)))
void gru_pipe_kernel(
    const float* __restrict__ dt,
    const float* __restrict__ values,
    const int*   __restrict__ meas,
    const float* __restrict__ kern,
    const float* __restrict__ bias,
    const float* __restrict__ demo,
    const int*   __restrict__ lengths,
    const float* __restrict__ W1,
    const float* __restrict__ b1,
    const float* __restrict__ W2,
    const float* __restrict__ b2,
    const float* __restrict__ rec_kernel,
    const float* __restrict__ Wo,
    const float* __restrict__ bo,
    float* __restrict__ out)
{
    __shared__ unsigned short sX[MTILE][XSTR];        // 34816 B (staging)
    __shared__ unsigned short sKT[TU][XSTR];          // 26112 B (K^T bf16)
    __shared__ unsigned short sXZ[2][MTILE][XZSTR];   // 52224 B (xz dbuf)
    __shared__ float sH[64];                          //   256 B

    const int b    = blockIdx.x;
    const int tid  = threadIdx.x;
    const int wave = tid >> 6;
    const int lane = tid & 63;
    const int len  = lengths[b];
    const int ntiles = (len + MTILE - 1) / MTILE;     // >= 1, block-uniform
    const int lr   = lane & 15;          // A-row / B-col / D-col
    const int lk   = (lane >> 4) * 8;    // k offset within frag

    // ---- prologue: sKT (coalesced), sX pad zero ----
    for (int idx = tid; idx < TU * KP; idx += 256) {
        int k = idx / TU;
        int j = idx - k * TU;
        sKT[j][k] = (k < TF) ? f2bf_rne(kern[k * TU + j]) : (unsigned short)0;
    }
    for (int i = tid; i < MTILE * (KP - TF); i += 256) {
        int t = i / (KP - TF), p = i - t * (KP - TF);
        sX[t][TF + p] = 0;
    }
    __syncthreads();

    float bi[6];
    #pragma unroll
    for (int n = 0; n < 6; ++n) bi[n] = bias[n * 16 + lr];
    short8 bfr[6][4];
    #pragma unroll
    for (int n = 0; n < 6; ++n)
        #pragma unroll
        for (int kc = 0; kc < 4; ++kc)
            bfr[n][kc] = *(const short8*)&sKT[n * 16 + lr][kc * 32 + lk];

    // MFMA one 32-row chunk of the tile at t0 into sXZ[buf]
    auto mfma_chunk = [&](int c, int buf) {
        f32x4 acc[2][6];
        #pragma unroll
        for (int m = 0; m < 2; ++m)
            #pragma unroll
            for (int n = 0; n < 6; ++n) acc[m][n] = (f32x4){0.f, 0.f, 0.f, 0.f};
        #pragma unroll
        for (int kc = 0; kc < 4; ++kc) {
            short8 a0 = *(const short8*)&sX[c * 32 + lr][kc * 32 + lk];
            short8 a1 = *(const short8*)&sX[c * 32 + 16 + lr][kc * 32 + lk];
            #pragma unroll
            for (int n = 0; n < 6; ++n) {
                acc[0][n] = __builtin_amdgcn_mfma_f32_16x16x32_bf16(a0, bfr[n][kc], acc[0][n], 0, 0, 0);
                acc[1][n] = __builtin_amdgcn_mfma_f32_16x16x32_bf16(a1, bfr[n][kc], acc[1][n], 0, 0, 0);
            }
        }
        #pragma unroll
        for (int m = 0; m < 2; ++m)
            #pragma unroll
            for (int r = 0; r < 4; ++r) {
                int row = c * 32 + m * 16 + (lane >> 4) * 4 + r;
                #pragma unroll
                for (int n = 0; n < 6; ++n)
                    sXZ[buf][row][lr + n * 16] = f2bf_rne(acc[m][n][r] + bi[n]);
            }
    };

    // ---- prologue: tile 0 (all 4 waves: strided staging, chunk w = wave) ----
    for (int i = tid; i < MTILE * F_; i += 256) {
        int t = i / F_, f = i - t * F_;
        size_t g = ((size_t)b * T_ + t) * F_ + f;
        sX[t][f]          = f2bf_rne(values[g]);
        sX[t][F_ + f]     = meas[g] ? (unsigned short)0x3F80 : (unsigned short)0;
        sX[t][2 * F_ + f] = f2bf_rne(dt[g]);
    }
    __syncthreads();
    mfma_chunk(wave, 0);
    __syncthreads();

    if (wave != 0) {
        // ------------- producer waves: tile k+1 during iteration k -------------
        for (int k = 0; k < ntiles; ++k) {
            if (k + 1 < ntiles) {
                const int t0n = (k + 1) * MTILE;
                const int buf = (k + 1) & 1;
                const int nch = (wave == 1) ? 2 : 1;
                for (int ci = 0; ci < nch; ++ci) {
                    const int c = (wave == 1) ? (ci == 0 ? 0 : 3) : (wave - 1);
                    // stage ONLY this chunk's rows (read back by same wave)
                    for (int i = lane; i < 32 * F_; i += 64) {
                        int tr = i / F_, f = i - tr * F_;
                        int t  = c * 32 + tr;
                        size_t g = ((size_t)b * T_ + (t0n + t)) * F_ + f;
                        sX[t][f]          = f2bf_rne(values[g]);
                        sX[t][F_ + f]     = meas[g] ? (unsigned short)0x3F80 : (unsigned short)0;
                        sX[t][2 * F_ + f] = f2bf_rne(dt[g]);
                    }
                    MEM_FENCE();   // wave-internal DS in-order: RAW safe
                    mfma_chunk(c, buf);
                }
            }
            __syncthreads();
        }
        return;   // no barriers after this point
    }

    // ------------------- consumer wave 0: recurrence -------------------
    const int l   = lane;
    const int lc  = l & 31;
    const bool lower = (l < 32);

    f32x2 wpA[16], wpB[16];
    #pragma unroll
    for (int m = 0; m < 16; ++m) {
        wpA[m] = (f32x2){-L2E * rec_kernel[(2 * m) * TU + l],
                         -L2E * rec_kernel[(2 * m + 1) * TU + l]};
        wpB[m] = (f32x2){2.f * L2E * rec_kernel[(2 * m) * TU + 64 + lc],
                         2.f * L2E * rec_kernel[(2 * m + 1) * TU + 64 + lc]};
    }
    float rbA = -L2E * bias[TU + l];
    float rbB = 2.f * L2E * bias[TU + 64 + lc];
    #pragma unroll
    for (int m = 0; m < 16; ++m) {
        asm volatile("" : "+v"(wpA[m]));
        asm volatile("" : "+v"(wpB[m]));
    }
    asm volatile("" : "+v"(rbA), "+v"(rbB));

    // h0 = relu(demo@W1+b1)@W2+b2
    float av = 0.f;
    if (l < U_) {
        float a = b1[l];
        #pragma unroll
        for (int d = 0; d < D_; ++d) a += demo[b * D_ + d] * W1[d * U_ + l];
        av = fmaxf(a, 0.f);
    }
    float hv = b2[lc];
    #pragma unroll
    for (int k = 0; k < U_; ++k) hv += rdlane(av, k) * W2[k * U_ + lc];

    typedef union { f32x4 q; f32x2 d[2]; } qd_u;
    unsigned short rA[4], rB[4];

    // xApre = -L2E*xA + rbA ; xBpre = 2L2E*xB
    auto step = [&](float xApre, float xBpre) {
        // R1: broadcast h via LDS crossbar (readlane occupancy fix, r9)
        sH[l] = hv;
        MEM_FENCE();
        qd_u hq[8];
        #pragma unroll
        for (int q = 0; q < 8; ++q)
            hq[q].q = *(const f32x4*)&sH[4 * q];   // uniform addr = broadcast
        MEM_FENCE();
        SCHED_FENCE();
        // R2: A-path matvec -> recA -> exp
        f32x2 aA0 = (f32x2){xApre, 0.f}, aA1, aA2, aA3;
        PKFMAV(aA0, hq[0].d[0], wpA[0]);
        PKMULV(aA1, hq[0].d[1], wpA[1]);
        PKMULV(aA2, hq[1].d[0], wpA[2]);
        PKMULV(aA3, hq[1].d[1], wpA[3]);
        #pragma unroll
        for (int g = 1; g < 4; ++g) {
            PKFMAV(aA0, hq[2 * g].d[0],     wpA[4 * g]);
            PKFMAV(aA1, hq[2 * g].d[1],     wpA[4 * g + 1]);
            PKFMAV(aA2, hq[2 * g + 1].d[0], wpA[4 * g + 2]);
            PKFMAV(aA3, hq[2 * g + 1].d[1], wpA[4 * g + 3]);
        }
        f32x2 tA01, tA23, tA;
        PKADD(tA01, aA0, aA1); PKADD(tA23, aA2, aA3); PKADD(tA, tA01, tA23);
        float recA = tA.x + tA.y;
        float eA = fast_exp2(recA);
        SCHED_FENCE();
        // R3: B-path first half — fills exp latency
        f32x2 aB0 = (f32x2){rbB, 0.f}, aB1, aB2, aB3;
        PKFMAV(aB0, hq[0].d[0], wpB[0]);
        PKMULV(aB1, hq[0].d[1], wpB[1]);
        PKMULV(aB2, hq[1].d[0], wpB[2]);
        PKMULV(aB3, hq[1].d[1], wpB[3]);
        PKFMAV(aB0, hq[2].d[0], wpB[4]);
        PKFMAV(aB1, hq[2].d[1], wpB[5]);
        PKFMAV(aB2, hq[3].d[0], wpB[6]);
        PKFMAV(aB3, hq[3].d[1], wpB[7]);
        SCHED_FENCE();
        float zr = fast_rcp(1.f + eA);       // z (l<32) | r (l>=32)
        SCHED_FENCE();
        // R4: B-path second half + tree — fills rcp latency
        #pragma unroll
        for (int g = 2; g < 4; ++g) {
            PKFMAV(aB0, hq[2 * g].d[0],     wpB[4 * g]);
            PKFMAV(aB1, hq[2 * g].d[1],     wpB[4 * g + 1]);
            PKFMAV(aB2, hq[2 * g + 1].d[0], wpB[4 * g + 2]);
            PKFMAV(aB3, hq[2 * g + 1].d[1], wpB[4 * g + 3]);
        }
        f32x2 tB01, tB23, tB;
        PKADD(tB01, aB0, aB1); PKADD(tB23, aB2, aB3); PKADD(tB, tB01, tB23);
        float recB = tB.x + tB.y;
        SCHED_FENCE();
        // R5: tail
        float sw = swap_half(zr);            // partner's value
        float z  = lower ? zr : sw;
        float r  = lower ? sw : zr;
        float u2 = fmaf(r, recB, xBpre);     // 2L2E*(xB + r*rec_h)
        float e2 = fast_exp2(u2);
        float hh = fmaf(-2.f, fast_rcp(e2 + 1.f), 1.f);  // tanh
        hv = fmaf(z, hv - hh, hh);
    };

    for (int k = 0; k < ntiles; ++k) {
        const int t0    = k * MTILE;
        const int left  = len - t0;
        const int steps = (left < MTILE) ? left : MTILE;   // >=1
        const unsigned short* xb = &sXZ[k & 1][0][0];

        auto rd4 = [&](int i0) {
            #pragma unroll
            for (int i = 0; i < 4; ++i) {
                int ii = i0 + i; ii = (ii < steps) ? ii : (steps - 1);
                rA[i] = xb[ii * XZSTR + l];        // x_z (l<32) | x_r
                rB[i] = xb[ii * XZSTR + 64 + lc];  // x_h
            }
        };

        rd4(0);
        const int fullt = steps & ~3;
        for (int ig = 0; ig < fullt; ig += 4) {
            float pA0 = fmaf(bf2f(rA[0]), -L2E, rbA), pB0 = bf2f(rB[0]) * (2.f * L2E);
            float pA1 = fmaf(bf2f(rA[1]), -L2E, rbA), pB1 = bf2f(rB[1]) * (2.f * L2E);
            float pA2 = fmaf(bf2f(rA[2]), -L2E, rbA), pB2 = bf2f(rB[2]) * (2.f * L2E);
            float pA3 = fmaf(bf2f(rA[3]), -L2E, rbA), pB3 = bf2f(rB[3]) * (2.f * L2E);
            rd4(ig + 4);                        // prefetch next group (LDS)
            step(pA0, pB0); step(pA1, pB1); step(pA2, pB2); step(pA3, pB3);
        }
        const int rem = steps - fullt;
        if (rem > 0) step(fmaf(bf2f(rA[0]), -L2E, rbA), bf2f(rB[0]) * (2.f * L2E));
        if (rem > 1) step(fmaf(bf2f(rA[1]), -L2E, rbA), bf2f(rB[1]) * (2.f * L2E));
        if (rem > 2) step(fmaf(bf2f(rA[2]), -L2E, rbA), bf2f(rB[2]) * (2.f * L2E));

        __syncthreads();   // tile k done; tile k+1 buffer now published
    }

    float v = (l < U_) ? hv * Wo[l] : 0.f;
    v += __shfl_xor(v, 16);
    v += __shfl_xor(v, 8);
    v += __shfl_xor(v, 4);
    v += __shfl_xor(v, 2);
    v += __shfl_xor(v, 1);
    if (l == 0) out[b] = sigmoid_fast(v + bo[0]);
}

extern "C" void kernel_launch(void* const* d_in, const int* in_sizes, int n_in,
                              void* d_out, int out_size, void* d_ws, size_t ws_size,
                              hipStream_t stream) {
    const float* demo       = (const float*)d_in[0];
    const float* dt         = (const float*)d_in[1];
    const float* values     = (const float*)d_in[2];
    const int*   meas       = (const int*)  d_in[3];
    const int*   lengths    = (const int*)  d_in[4];
    const float* W1         = (const float*)d_in[5];
    const float* b1         = (const float*)d_in[6];
    const float* W2         = (const float*)d_in[7];
    const float* b2         = (const float*)d_in[8];
    const float* kern       = (const float*)d_in[9];
    const float* rec_kernel = (const float*)d_in[10];
    const float* bias       = (const float*)d_in[11];
    const float* Wo         = (const float*)d_in[12];
    const float* bo         = (const float*)d_in[13];
    float* out = (float*)d_out;

    hipLaunchKernelGGL(gru_pipe_kernel, dim3(B_), dim3(256), 0, stream,
                       dt, values, meas, kern, bias, demo, lengths,
                       W1, b1, W2, b2, rec_kernel, Wo, bo, out);
}

// Round 15
// 393.336 us; speedup vs baseline: 1.4007x; 1.0887x over previous
//
#include <hip/hip_runtime.h>

#define B_    256
#define T_    2048
#define F_    37
#define TF    111   // 3F
#define U_    32
#define TU    96    // 3U
#define D_    16

#define KP    128   // padded K for MFMA
#define XSTR  136   // LDS row stride in bf16 (staging)
#define TSTR  132   // LDS row stride of transposed xz tile (264 B, 8B-aligned)
#define MTILE 128   // timesteps per tile

#define L2E 1.4426950408889634f

typedef __attribute__((ext_vector_type(8))) short short8;
typedef __attribute__((ext_vector_type(4))) short s16x4;
typedef __attribute__((ext_vector_type(4))) float f32x4;
typedef __attribute__((ext_vector_type(2))) float f32x2;
typedef __attribute__((ext_vector_type(2))) unsigned uint2v;

__device__ __forceinline__ float fast_exp2(float x) {
    float r; asm("v_exp_f32 %0, %1" : "=v"(r) : "v"(x)); return r;
}
__device__ __forceinline__ float fast_rcp(float x) {
    float r; asm("v_rcp_f32 %0, %1" : "=v"(r) : "v"(x)); return r;
}
__device__ __forceinline__ float sigmoid_fast(float x) {
    return fast_rcp(1.f + fast_exp2(-L2E * x));
}
__device__ __forceinline__ float rdlane(float v, int k) {
    return __uint_as_float(__builtin_amdgcn_readlane(__float_as_uint(v), k));
}
// every lane gets its cross-32 partner's value (hedge: partner = p0+p1-own)
__device__ __forceinline__ float swap_half(float x) {
    unsigned xi = __float_as_uint(x);
    auto p = __builtin_amdgcn_permlane32_swap(xi, xi, false, false);
    float f0 = __uint_as_float(p[0]);
    float f1 = __uint_as_float(p[1]);
    return (f0 + f1) - x;
}
__device__ __forceinline__ float bf2f(unsigned short u) {
    return __uint_as_float(((unsigned)u) << 16);
}
__device__ __forceinline__ unsigned short f2bf_rne(float x) {
    unsigned u = __float_as_uint(x);
    return (unsigned short)((u + 0x7FFFu + ((u >> 16) & 1u)) >> 16);
}
__device__ __forceinline__ unsigned pk_bf16(float a, float b) {
    unsigned u;
    asm("v_cvt_pk_bf16_f32 %0, %1, %2" : "=v"(u) : "v"(a), "v"(b));
    return u;
}

// packed f32 math, all-VGPR operands
#define PKMULV(d, hq, w) \
    asm("v_pk_mul_f32 %0, %1, %2" : "=v"(d) : "v"(hq), "v"(w))
#define PKFMAV(d, hq, w) \
    asm("v_pk_fma_f32 %0, %1, %2, %0" : "+v"(d) : "v"(hq), "v"(w))
#define PKADD(d, a, b) \
    asm("v_pk_add_f32 %0, %1, %2" : "=v"(d) : "v"(a), "v"(b))

#define SCHED_FENCE() __builtin_amdgcn_sched_barrier(0)
#define MEM_FENCE()   asm volatile("" ::: "memory")

// ============================================================================
// Pipelined fused kernel (r12 structure, DS-traffic diet; r14 = meas-index fix):
// 256 blocks (one per batch) x 256 threads (4 waves, 1/SIMD).
// Wave 0 runs the recurrence on LDS xz tile k while waves 1-3 build tile k+1
// (one __syncthreads per tile). The LDS pipe is per-CU and shared — the
// consumer's critical path is a DS round-trip per step — so producer DS ops
// are minimized (VALU on other SIMDs is free):
//   - staging writes pk_bf16-packed b32 (56/row vs 111 b16)
//   - xz tile TRANSPOSED [col][time]: producer publishes b64 quads
//     (12/chunk vs 48 b16), consumer reads 4 steps as 2 b64 (vs 8 b16)
// Same math/rounding as r12 (RNE everywhere) -> absmax unchanged.
// ============================================================================
__global__ __attribute__((amdgpu_flat_work_group_size(256, 256),
                          amdgpu_waves_per_eu(1, 1)))
void gru_pipe2_kernel(
    const float* __restrict__ dt,
    const float* __restrict__ values,
    const int*   __restrict__ meas,
    const float* __restrict__ kern,
    const float* __restrict__ bias,
    const float* __restrict__ demo,
    const int*   __restrict__ lengths,
    const float* __restrict__ W1,
    const float* __restrict__ b1,
    const float* __restrict__ W2,
    const float* __restrict__ b2,
    const float* __restrict__ rec_kernel,
    const float* __restrict__ Wo,
    const float* __restrict__ bo,
    float* __restrict__ out)
{
    __shared__ unsigned short sX[MTILE][XSTR];      // 34816 B (staging)
    __shared__ unsigned short sKT[TU][XSTR];        // 26112 B (K^T bf16)
    __shared__ unsigned short sXZ[2][TU][TSTR];     // 50688 B (xz dbuf, transposed)
    __shared__ float sH[64];                        //   256 B  => 111872 B total

    const int b    = blockIdx.x;
    const int tid  = threadIdx.x;
    const int wave = tid >> 6;
    const int lane = tid & 63;
    const int len  = lengths[b];
    const int ntiles = (len + MTILE - 1) / MTILE;   // >= 1, block-uniform
    const int lr   = lane & 15;          // A-row / B-col / D-col
    const int lk   = (lane >> 4) * 8;    // k offset within frag

    // ---- prologue: sKT (coalesced), sX pad zero ----
    for (int idx = tid; idx < TU * KP; idx += 256) {
        int k = idx / TU;
        int j = idx - k * TU;
        sKT[j][k] = (k < TF) ? f2bf_rne(kern[k * TU + j]) : (unsigned short)0;
    }
    for (int i = tid; i < MTILE * (KP - TF); i += 256) {
        int t = i / (KP - TF), p = i - t * (KP - TF);
        sX[t][TF + p] = 0;
    }
    __syncthreads();

    float bi[6];
    #pragma unroll
    for (int n = 0; n < 6; ++n) bi[n] = bias[n * 16 + lr];
    short8 bfr[6][4];
    #pragma unroll
    for (int n = 0; n < 6; ++n)
        #pragma unroll
        for (int kc = 0; kc < 4; ++kc)
            bfr[n][kc] = *(const short8*)&sKT[n * 16 + lr][kc * 32 + lk];

    // stage one 32-row chunk of tile t0 into sX — packed b32 writes.
    // dest cols: [0..35]=values f0..35 pairs, 36|37=(values36, meas0),
    // 38..73=meas f1..36 pairs, 74..109=dt f0..35 pairs, 110|111=(dt36, 0).
    // Source index = feature index within the SAME row (no F_ offset!).
    auto stage_chunk = [&](int c, int t0) {
        for (int i = lane; i < 32 * 18; i += 64) {
            int tr = i / 18, p = i - tr * 18;
            int t = c * 32 + tr;
            size_t g = ((size_t)b * T_ + (t0 + t)) * F_;
            *(unsigned*)&sX[t][2 * p] =
                pk_bf16(values[g + 2 * p], values[g + 2 * p + 1]);
            *(unsigned*)&sX[t][38 + 2 * p] =
                pk_bf16(meas[g + 1 + 2 * p] ? 1.f : 0.f,
                        meas[g + 2 + 2 * p] ? 1.f : 0.f);
            *(unsigned*)&sX[t][74 + 2 * p] =
                pk_bf16(dt[g + 2 * p], dt[g + 2 * p + 1]);
        }
        if (lane < 32) {
            int t = c * 32 + lane;
            size_t g = ((size_t)b * T_ + (t0 + t)) * F_;
            *(unsigned*)&sX[t][36] =
                pk_bf16(values[g + 36], meas[g] ? 1.f : 0.f);
            *(unsigned*)&sX[t][110] = pk_bf16(dt[g + 36], 0.f);
        }
    };

    // MFMA one 32-row chunk into the TRANSPOSED xz buffer (b64 quad writes)
    auto mfma_chunk = [&](int c, int buf) {
        f32x4 acc[2][6];
        #pragma unroll
        for (int m = 0; m < 2; ++m)
            #pragma unroll
            for (int n = 0; n < 6; ++n) acc[m][n] = (f32x4){0.f, 0.f, 0.f, 0.f};
        #pragma unroll
        for (int kc = 0; kc < 4; ++kc) {
            short8 a0 = *(const short8*)&sX[c * 32 + lr][kc * 32 + lk];
            short8 a1 = *(const short8*)&sX[c * 32 + 16 + lr][kc * 32 + lk];
            #pragma unroll
            for (int n = 0; n < 6; ++n) {
                acc[0][n] = __builtin_amdgcn_mfma_f32_16x16x32_bf16(a0, bfr[n][kc], acc[0][n], 0, 0, 0);
                acc[1][n] = __builtin_amdgcn_mfma_f32_16x16x32_bf16(a1, bfr[n][kc], acc[1][n], 0, 0, 0);
            }
        }
        #pragma unroll
        for (int m = 0; m < 2; ++m) {
            const int tb = c * 32 + m * 16 + (lane >> 4) * 4;   // 4-aligned
            #pragma unroll
            for (int n = 0; n < 6; ++n) {
                unsigned lo = pk_bf16(acc[m][n][0] + bi[n], acc[m][n][1] + bi[n]);
                unsigned hi = pk_bf16(acc[m][n][2] + bi[n], acc[m][n][3] + bi[n]);
                *(uint2v*)&sXZ[buf][lr + n * 16][tb] = (uint2v){lo, hi};
            }
        }
    };

    // ---- prologue: tile 0 — each wave stages + MFMAs its own chunk ----
    stage_chunk(wave, 0);
    MEM_FENCE();                 // wave-internal DS in-order: RAW safe
    mfma_chunk(wave, 0);
    __syncthreads();             // tile 0 published; sX free for tile 1

    if (wave != 0) {
        // ---------- producer waves: tile k+1 during iteration k ----------
        for (int k = 0; k < ntiles; ++k) {
            if (k + 1 < ntiles) {
                const int t0n = (k + 1) * MTILE;
                const int buf = (k + 1) & 1;
                const int nch = (wave == 1) ? 2 : 1;
                for (int ci = 0; ci < nch; ++ci) {
                    const int c = (wave == 1) ? (ci == 0 ? 0 : 3) : (wave - 1);
                    stage_chunk(c, t0n);
                    MEM_FENCE();
                    mfma_chunk(c, buf);
                }
            }
            __syncthreads();
        }
        return;   // no barriers after this point
    }

    // ------------------- consumer wave 0: recurrence -------------------
    const int l   = lane;
    const int lc  = l & 31;
    const bool lower = (l < 32);

    f32x2 wpA[16], wpB[16];
    #pragma unroll
    for (int m = 0; m < 16; ++m) {
        wpA[m] = (f32x2){-L2E * rec_kernel[(2 * m) * TU + l],
                         -L2E * rec_kernel[(2 * m + 1) * TU + l]};
        wpB[m] = (f32x2){2.f * L2E * rec_kernel[(2 * m) * TU + 64 + lc],
                         2.f * L2E * rec_kernel[(2 * m + 1) * TU + 64 + lc]};
    }
    float rbA = -L2E * bias[TU + l];
    float rbB = 2.f * L2E * bias[TU + 64 + lc];
    #pragma unroll
    for (int m = 0; m < 16; ++m) {
        asm volatile("" : "+v"(wpA[m]));
        asm volatile("" : "+v"(wpB[m]));
    }
    asm volatile("" : "+v"(rbA), "+v"(rbB));

    // h0 = relu(demo@W1+b1)@W2+b2
    float av = 0.f;
    if (l < U_) {
        float a = b1[l];
        #pragma unroll
        for (int d = 0; d < D_; ++d) a += demo[b * D_ + d] * W1[d * U_ + l];
        av = fmaxf(a, 0.f);
    }
    float hv = b2[lc];
    #pragma unroll
    for (int k = 0; k < U_; ++k) hv += rdlane(av, k) * W2[k * U_ + lc];

    typedef union { f32x4 q; f32x2 d[2]; } qd_u;
    typedef union { s16x4 v; unsigned short u[4]; } s4u;

    // xApre = -L2E*xA + rbA ; xBpre = 2L2E*xB
    auto step = [&](float xApre, float xBpre) {
        // R1: broadcast h via LDS crossbar (readlane occupancy fix, r9)
        sH[l] = hv;
        MEM_FENCE();
        qd_u hq[8];
        #pragma unroll
        for (int q = 0; q < 8; ++q)
            hq[q].q = *(const f32x4*)&sH[4 * q];   // uniform addr = broadcast
        MEM_FENCE();
        SCHED_FENCE();
        // R2: A-path matvec -> recA -> exp
        f32x2 aA0 = (f32x2){xApre, 0.f}, aA1, aA2, aA3;
        PKFMAV(aA0, hq[0].d[0], wpA[0]);
        PKMULV(aA1, hq[0].d[1], wpA[1]);
        PKMULV(aA2, hq[1].d[0], wpA[2]);
        PKMULV(aA3, hq[1].d[1], wpA[3]);
        #pragma unroll
        for (int g = 1; g < 4; ++g) {
            PKFMAV(aA0, hq[2 * g].d[0],     wpA[4 * g]);
            PKFMAV(aA1, hq[2 * g].d[1],     wpA[4 * g + 1]);
            PKFMAV(aA2, hq[2 * g + 1].d[0], wpA[4 * g + 2]);
            PKFMAV(aA3, hq[2 * g + 1].d[1], wpA[4 * g + 3]);
        }
        f32x2 tA01, tA23, tA;
        PKADD(tA01, aA0, aA1); PKADD(tA23, aA2, aA3); PKADD(tA, tA01, tA23);
        float recA = tA.x + tA.y;
        float eA = fast_exp2(recA);
        SCHED_FENCE();
        // R3: B-path first half — fills exp latency
        f32x2 aB0 = (f32x2){rbB, 0.f}, aB1, aB2, aB3;
        PKFMAV(aB0, hq[0].d[0], wpB[0]);
        PKMULV(aB1, hq[0].d[1], wpB[1]);
        PKMULV(aB2, hq[1].d[0], wpB[2]);
        PKMULV(aB3, hq[1].d[1], wpB[3]);
        PKFMAV(aB0, hq[2].d[0], wpB[4]);
        PKFMAV(aB1, hq[2].d[1], wpB[5]);
        PKFMAV(aB2, hq[3].d[0], wpB[6]);
        PKFMAV(aB3, hq[3].d[1], wpB[7]);
        SCHED_FENCE();
        float zr = fast_rcp(1.f + eA);       // z (l<32) | r (l>=32)
        SCHED_FENCE();
        // R4: B-path second half + tree — fills rcp latency
        #pragma unroll
        for (int g = 2; g < 4; ++g) {
            PKFMAV(aB0, hq[2 * g].d[0],     wpB[4 * g]);
            PKFMAV(aB1, hq[2 * g].d[1],     wpB[4 * g + 1]);
            PKFMAV(aB2, hq[2 * g + 1].d[0], wpB[4 * g + 2]);
            PKFMAV(aB3, hq[2 * g + 1].d[1], wpB[4 * g + 3]);
        }
        f32x2 tB01, tB23, tB;
        PKADD(tB01, aB0, aB1); PKADD(tB23, aB2, aB3); PKADD(tB, tB01, tB23);
        float recB = tB.x + tB.y;
        SCHED_FENCE();
        // R5: tail
        float sw = swap_half(zr);            // partner's value
        float z  = lower ? zr : sw;
        float r  = lower ? sw : zr;
        float u2 = fmaf(r, recB, xBpre);     // 2L2E*(xB + r*rec_h)
        float e2 = fast_exp2(u2);
        float hh = fmaf(-2.f, fast_rcp(e2 + 1.f), 1.f);  // tanh
        hv = fmaf(z, hv - hh, hh);
    };

    for (int k = 0; k < ntiles; ++k) {
        const int left  = len - k * MTILE;
        const int steps = (left < MTILE) ? left : MTILE;   // >= 1
        const int kb    = k & 1;

        s4u a4, b4;
        auto rd4 = [&](int i0) {    // 4 steps of rA + rB: two b64 LDS reads
            a4.v = *(const s16x4*)&sXZ[kb][l][i0];
            b4.v = *(const s16x4*)&sXZ[kb][64 + lc][i0];
        };

        rd4(0);
        const int fullt = steps & ~3;
        for (int ig = 0; ig < fullt; ig += 4) {
            float pA0 = fmaf(bf2f(a4.u[0]), -L2E, rbA), pB0 = bf2f(b4.u[0]) * (2.f * L2E);
            float pA1 = fmaf(bf2f(a4.u[1]), -L2E, rbA), pB1 = bf2f(b4.u[1]) * (2.f * L2E);
            float pA2 = fmaf(bf2f(a4.u[2]), -L2E, rbA), pB2 = bf2f(b4.u[2]) * (2.f * L2E);
            float pA3 = fmaf(bf2f(a4.u[3]), -L2E, rbA), pB3 = bf2f(b4.u[3]) * (2.f * L2E);
            rd4(ig + 4);                       // prefetch next group (LDS; in-bounds pad)
            step(pA0, pB0); step(pA1, pB1); step(pA2, pB2); step(pA3, pB3);
        }
        const int rem = steps - fullt;
        if (rem > 0) step(fmaf(bf2f(a4.u[0]), -L2E, rbA), bf2f(b4.u[0]) * (2.f * L2E));
        if (rem > 1) step(fmaf(bf2f(a4.u[1]), -L2E, rbA), bf2f(b4.u[1]) * (2.f * L2E));
        if (rem > 2) step(fmaf(bf2f(a4.u[2]), -L2E, rbA), bf2f(b4.u[2]) * (2.f * L2E));

        __syncthreads();   // tile k consumed; tile k+1 buffer published
    }

    float v = (l < U_) ? hv * Wo[l] : 0.f;
    v += __shfl_xor(v, 16);
    v += __shfl_xor(v, 8);
    v += __shfl_xor(v, 4);
    v += __shfl_xor(v, 2);
    v += __shfl_xor(v, 1);
    if (l == 0) out[b] = sigmoid_fast(v + bo[0]);
}

extern "C" void kernel_launch(void* const* d_in, const int* in_sizes, int n_in,
                              void* d_out, int out_size, void* d_ws, size_t ws_size,
                              hipStream_t stream) {
    const float* demo       = (const float*)d_in[0];
    const float* dt         = (const float*)d_in[1];
    const float* values     = (const float*)d_in[2];
    const int*   meas       = (const int*)  d_in[3];
    const int*   lengths    = (const int*)  d_in[4];
    const float* W1         = (const float*)d_in[5];
    const float* b1         = (const float*)d_in[6];
    const float* W2         = (const float*)d_in[7];
    const float* b2         = (const float*)d_in[8];
    const float* kern       = (const float*)d_in[9];
    const float* rec_kernel = (const float*)d_in[10];
    const float* bias       = (const float*)d_in[11];
    const float* Wo         = (const float*)d_in[12];
    const float* bo         = (const float*)d_in[13];
    float* out = (float*)d_out;

    hipLaunchKernelGGL(gru_pipe2_kernel, dim3(B_), dim3(256), 0, stream,
                       dt, values, meas, kern, bias, demo, lengths,
                       W1, b1, W2, b2, rec_kernel, Wo, bo, out);
}